// Round 1
// baseline (210.416 us; speedup 1.0000x reference)
//
#include <hip/hip_runtime.h>

#define NB   8192
#define HD   1024
#define HFD  1152
#define NK0  64
#define NK1  256
#define DD   128

typedef __attribute__((ext_vector_type(4))) float  f32x4;
typedef __attribute__((ext_vector_type(8))) __bf16 bf16x8;

__device__ __forceinline__ unsigned short f2bf(float f) {
  unsigned int u = __float_as_uint(f);
  u += 0x7fffu + ((u >> 16) & 1u);
  return (unsigned short)(u >> 16);
}
__device__ __forceinline__ float bf2f(unsigned short h) {
  return __uint_as_float(((unsigned int)h) << 16);
}
__device__ __forceinline__ unsigned int pack2(float a, float b) {
  return (unsigned int)f2bf(a) | ((unsigned int)f2bf(b) << 16);
}

// ---------------- Kernel 1: GEMM1 + LN + coarse VQ -------------------------
// tile: BM=64 rows, BN=128 (=DC, full), BK=64. 4 waves (256 thr).
__global__ __launch_bounds__(256) void k1_gemm_ln_coarse(
    const float* __restrict__ x, const float* __restrict__ Wc,
    const float* __restrict__ bc, const float* __restrict__ gc,
    const float* __restrict__ betac, const float* __restrict__ ccb,
    float* __restrict__ out0, unsigned short* __restrict__ zcq_bf,
    int* __restrict__ ci_g, int* __restrict__ counts,
    float* __restrict__ coarse_partial)
{
  extern __shared__ char smem[];
  unsigned short* As = (unsigned short*)smem;            // [64][72] bf16
  unsigned short* Bs = (unsigned short*)(smem + 9216);   // [128][72] bf16
  float* zcL   = (float*)smem;                           // [64][133] f32 (overlay)
  float* cbL   = (float*)(smem + 34048);                 // [64][133] f32
  float* cnorm = (float*)(smem + 68096);                 // [64]
  float* dmS   = (float*)(smem + 68352);                 // [4][64]
  int*   imS   = (int*)  (smem + 69376);                 // [4][64]
  int*   cxS   = (int*)  (smem + 70400);                 // [64]
  float* redS  = (float*)(smem + 70656);                 // [4]

  const int t    = threadIdx.x;
  const int lane = t & 63;
  const int wid  = t >> 6;
  const int wm = wid & 1, wn = wid >> 1;
  const int m0 = blockIdx.x * 64;
  const int l15 = lane & 15, lhi = lane >> 4;

  f32x4 acc[2][4];
#pragma unroll
  for (int m = 0; m < 2; ++m)
#pragma unroll
    for (int n = 0; n < 4; ++n) acc[m][n] = (f32x4){0.f, 0.f, 0.f, 0.f};

  for (int kt = 0; kt < HD / 64; ++kt) {
    __syncthreads();
#pragma unroll
    for (int i = 0; i < 4; ++i) {            // A: 64x64 f32 -> bf16
      int idx = t + i * 256;
      int row = idx >> 4, c4 = (idx & 15) << 2;
      const float4 v = *(const float4*)&x[(size_t)(m0 + row) * HD + kt * 64 + c4];
      *(uint2*)&As[row * 72 + c4] = make_uint2(pack2(v.x, v.y), pack2(v.z, v.w));
    }
#pragma unroll
    for (int i = 0; i < 8; ++i) {            // B: 128x64 (Wc rows, K-contig)
      int idx = t + i * 256;
      int row = idx >> 4, c4 = (idx & 15) << 2;
      const float4 v = *(const float4*)&Wc[(size_t)row * HD + kt * 64 + c4];
      *(uint2*)&Bs[row * 72 + c4] = make_uint2(pack2(v.x, v.y), pack2(v.z, v.w));
    }
    __syncthreads();
#pragma unroll
    for (int ks = 0; ks < 2; ++ks) {
      const int lk = ks * 32 + (lhi << 3);
      bf16x8 a0 = *(const bf16x8*)&As[(wm * 32 + l15) * 72 + lk];
      bf16x8 a1 = *(const bf16x8*)&As[(wm * 32 + 16 + l15) * 72 + lk];
#pragma unroll
      for (int n = 0; n < 4; ++n) {
        bf16x8 b = *(const bf16x8*)&Bs[(wn * 64 + n * 16 + l15) * 72 + lk];
        acc[0][n] = __builtin_amdgcn_mfma_f32_16x16x32_bf16(a0, b, acc[0][n], 0, 0, 0);
        acc[1][n] = __builtin_amdgcn_mfma_f32_16x16x32_bf16(a1, b, acc[1][n], 0, 0, 0);
      }
    }
  }
  __syncthreads();
  // acc -> zcL (+bias).  C/D map: col=lane&15, row=(lane>>4)*4+reg
#pragma unroll
  for (int m = 0; m < 2; ++m)
#pragma unroll
    for (int n = 0; n < 4; ++n)
#pragma unroll
      for (int r = 0; r < 4; ++r) {
        int row = wm * 32 + m * 16 + (lhi << 2) + r;
        int col = wn * 64 + n * 16 + l15;
        zcL[row * 133 + col] = acc[m][n][r] + bc[col];
      }
  // stage coarse codebook (fp32, exact for output gather)
#pragma unroll
  for (int i = 0; i < 8; ++i) {
    int idx = t + i * 256;
    int row = idx >> 5, c4 = (idx & 31) << 2;
    const float4 v = *(const float4*)&ccb[(size_t)row * DD + c4];
    float* dst = &cbL[row * 133 + c4];
    dst[0] = v.x; dst[1] = v.y; dst[2] = v.z; dst[3] = v.w;
  }
  __syncthreads();
  {  // LayerNorm: 4 threads per row; then codebook norms with same pattern
    const int r = t >> 2, p = t & 3;
    float* zr = &zcL[r * 133 + p * 32];
    float s = 0.f, s2 = 0.f;
#pragma unroll
    for (int j = 0; j < 32; ++j) { float v = zr[j]; s += v; s2 += v * v; }
    s  += __shfl_xor(s, 1);  s  += __shfl_xor(s, 2);
    s2 += __shfl_xor(s2, 1); s2 += __shfl_xor(s2, 2);
    const float mu   = s * (1.f / 128.f);
    const float var  = s2 * (1.f / 128.f) - mu * mu;
    const float rstd = rsqrtf(var + 1e-5f);
#pragma unroll
    for (int j = 0; j < 32; ++j) {
      int col = p * 32 + j;
      zr[j] = (zr[j] - mu) * rstd * gc[col] + betac[col];
    }
    const float* cr = &cbL[r * 133 + p * 32];
    float cs = 0.f;
#pragma unroll
    for (int j = 0; j < 32; ++j) { float v = cr[j]; cs += v * v; }
    cs += __shfl_xor(cs, 1); cs += __shfl_xor(cs, 2);
    if (p == 0) cnorm[r] = cs;
  }
  __syncthreads();
  {  // coarse distances: thread = (row=lane, code-group=wid of 16 codes)
    const int r = lane, cg = wid;
    float dacc[16];
#pragma unroll
    for (int j = 0; j < 16; ++j) dacc[j] = 0.f;
    for (int k = 0; k < 128; ++k) {
      float zv = zcL[r * 133 + k];
#pragma unroll
      for (int j = 0; j < 16; ++j) dacc[j] += zv * cbL[(cg * 16 + j) * 133 + k];
    }
    float best = 3.4e38f; int bidx = 0;
#pragma unroll
    for (int j = 0; j < 16; ++j) {
      int c = cg * 16 + j;
      float d = cnorm[c] - 2.f * dacc[j];
      if (d < best) { best = d; bidx = c; }
    }
    dmS[cg * 64 + r] = best;
    imS[cg * 64 + r] = bidx;
  }
  __syncthreads();
  if (t < 64) {
    float best = dmS[t]; int bidx = imS[t];
#pragma unroll
    for (int cg = 1; cg < 4; ++cg) {
      float d = dmS[cg * 64 + t]; int i2 = imS[cg * 64 + t];
      if (d < best || (d == best && i2 < bidx)) { best = d; bidx = i2; }
    }
    ci_g[m0 + t] = bidx;
    atomicAdd(&counts[bidx], 1);
    cxS[t] = bidx;
  }
  __syncthreads();
  float lp = 0.f;
#pragma unroll
  for (int i = 0; i < 32; ++i) {  // coalesced zcq output + bf16 copy + loss
    int e = t + i * 256;
    int r = e >> 7, col = e & 127;
    int c = cxS[r];
    float q = cbL[c * 133 + col];
    float z = zcL[r * 133 + col];
    out0[(size_t)(m0 + r) * DD + col]   = q;
    zcq_bf[(size_t)(m0 + r) * DD + col] = f2bf(q);
    float d = q - z; lp += d * d;
  }
#pragma unroll
  for (int off = 1; off < 64; off <<= 1) lp += __shfl_xor(lp, off);
  if (lane == 0) redS[wid] = lp;
  __syncthreads();
  if (t == 0) coarse_partial[blockIdx.x] = redS[0] + redS[1] + redS[2] + redS[3];
}

// ---------------- Kernel 2: GEMM2 (concat) + LN -> z_f bf16 ----------------
__global__ __launch_bounds__(256) void k2_gemm_ln(
    const float* __restrict__ x, const unsigned short* __restrict__ zcq_bf,
    const float* __restrict__ Wf, const float* __restrict__ bfv,
    const float* __restrict__ gf, const float* __restrict__ betaf,
    unsigned short* __restrict__ zf_bf)
{
  extern __shared__ char smem[];
  unsigned short* As = (unsigned short*)smem;            // [64][72]
  unsigned short* Bs = (unsigned short*)(smem + 9216);   // [128][72]
  float* zcL = (float*)smem;                             // [64][132] overlay

  const int t = threadIdx.x;
  const int lane = t & 63, wid = t >> 6;
  const int wm = wid & 1, wn = wid >> 1;
  const int m0 = blockIdx.x * 64;
  const int l15 = lane & 15, lhi = lane >> 4;

  f32x4 acc[2][4];
#pragma unroll
  for (int m = 0; m < 2; ++m)
#pragma unroll
    for (int n = 0; n < 4; ++n) acc[m][n] = (f32x4){0.f, 0.f, 0.f, 0.f};

  for (int kt = 0; kt < HFD / 64; ++kt) {   // 18 tiles: 16 from x, 2 from zcq
    __syncthreads();
    if (kt < 16) {
#pragma unroll
      for (int i = 0; i < 4; ++i) {
        int idx = t + i * 256;
        int row = idx >> 4, c4 = (idx & 15) << 2;
        const float4 v = *(const float4*)&x[(size_t)(m0 + row) * HD + kt * 64 + c4];
        *(uint2*)&As[row * 72 + c4] = make_uint2(pack2(v.x, v.y), pack2(v.z, v.w));
      }
    } else {
#pragma unroll
      for (int i = 0; i < 2; ++i) {
        int idx = t + i * 256;
        int row = idx >> 3, c8 = (idx & 7) << 3;
        const uint4 v = *(const uint4*)&zcq_bf[(size_t)(m0 + row) * DD + (kt - 16) * 64 + c8];
        *(uint4*)&As[row * 72 + c8] = v;
      }
    }
#pragma unroll
    for (int i = 0; i < 8; ++i) {
      int idx = t + i * 256;
      int row = idx >> 4, c4 = (idx & 15) << 2;
      const float4 v = *(const float4*)&Wf[(size_t)row * HFD + kt * 64 + c4];
      *(uint2*)&Bs[row * 72 + c4] = make_uint2(pack2(v.x, v.y), pack2(v.z, v.w));
    }
    __syncthreads();
#pragma unroll
    for (int ks = 0; ks < 2; ++ks) {
      const int lk = ks * 32 + (lhi << 3);
      bf16x8 a0 = *(const bf16x8*)&As[(wm * 32 + l15) * 72 + lk];
      bf16x8 a1 = *(const bf16x8*)&As[(wm * 32 + 16 + l15) * 72 + lk];
#pragma unroll
      for (int n = 0; n < 4; ++n) {
        bf16x8 b = *(const bf16x8*)&Bs[(wn * 64 + n * 16 + l15) * 72 + lk];
        acc[0][n] = __builtin_amdgcn_mfma_f32_16x16x32_bf16(a0, b, acc[0][n], 0, 0, 0);
        acc[1][n] = __builtin_amdgcn_mfma_f32_16x16x32_bf16(a1, b, acc[1][n], 0, 0, 0);
      }
    }
  }
  __syncthreads();
#pragma unroll
  for (int m = 0; m < 2; ++m)
#pragma unroll
    for (int n = 0; n < 4; ++n)
#pragma unroll
      for (int r = 0; r < 4; ++r) {
        int row = wm * 32 + m * 16 + (lhi << 2) + r;
        int col = wn * 64 + n * 16 + l15;
        zcL[row * 132 + col] = acc[m][n][r] + bfv[col];
      }
  __syncthreads();
  {  // LayerNorm
    const int r = t >> 2, p = t & 3;
    float* zr = &zcL[r * 132 + p * 32];
    float s = 0.f, s2 = 0.f;
#pragma unroll
    for (int j = 0; j < 32; ++j) { float v = zr[j]; s += v; s2 += v * v; }
    s  += __shfl_xor(s, 1);  s  += __shfl_xor(s, 2);
    s2 += __shfl_xor(s2, 1); s2 += __shfl_xor(s2, 2);
    const float mu   = s * (1.f / 128.f);
    const float var  = s2 * (1.f / 128.f) - mu * mu;
    const float rstd = rsqrtf(var + 1e-5f);
#pragma unroll
    for (int j = 0; j < 32; ++j) {
      int col = p * 32 + j;
      zr[j] = (zr[j] - mu) * rstd * gf[col] + betaf[col];
    }
  }
  __syncthreads();
#pragma unroll
  for (int i = 0; i < 32; ++i) {  // z_f -> bf16, coalesced
    int e = t + i * 256;
    int r = e >> 7, col = e & 127;
    zf_bf[(size_t)(m0 + r) * DD + col] = f2bf(zcL[r * 132 + col]);
  }
}

// ---------------- bucketing ------------------------------------------------
__global__ void k_prefix(const int* __restrict__ counts, int* __restrict__ offsets,
                         int* __restrict__ cursor) {
  if (threadIdx.x == 0) {
    int run = 0;
    for (int g = 0; g < NK0; ++g) { offsets[g] = run; cursor[g] = run; run += counts[g]; }
  }
}

__global__ void k_scatter(const int* __restrict__ ci_g, int* __restrict__ cursor,
                          int* __restrict__ bucket_rows) {
  int i = blockIdx.x * 256 + threadIdx.x;
  int c = ci_g[i];
  int pos = atomicAdd(&cursor[c], 1);
  bucket_rows[pos] = i;
}

// ---------------- Kernel 3: per-group fine VQ (MFMA) -----------------------
__global__ __launch_bounds__(256) void k3_fine(
    const unsigned short* __restrict__ zf_bf, const float* __restrict__ fcb,
    const int* __restrict__ counts, const int* __restrict__ offsets,
    const int* __restrict__ bucket_rows,
    float* __restrict__ out1, float* __restrict__ fine_partial)
{
  extern __shared__ char smem[];
  unsigned short* Vb   = (unsigned short*)smem;            // [256][136] bf16
  unsigned short* zfL  = (unsigned short*)(smem + 69632);  // [32][136] bf16
  float* cnorm = (float*)(smem + 78336);                   // [256]
  float* dist  = (float*)(smem + 79360);                   // [32][257]
  int*   fiS   = (int*)  (smem + 112256);                  // [32]
  int*   ridS  = (int*)  (smem + 112384);                  // [32]
  float* redS  = (float*)(smem + 112512);                  // [4]

  const int g = blockIdx.x;
  const int t = threadIdx.x;
  const int lane = t & 63, wid = t >> 6;
  const int l15 = lane & 15, lhi = lane >> 4;
  const int count = counts[g];
  const int start = offsets[g];

  cnorm[t] = 0.f;
  __syncthreads();
#pragma unroll
  for (int i = 0; i < 32; ++i) {   // stage group codebook + fp32 norms
    int idx = t + i * 256;
    int row = idx >> 5, c4 = (idx & 31) << 2;
    const float4 v = *(const float4*)&fcb[((size_t)g * NK1 + row) * DD + c4];
    *(uint2*)&Vb[row * 136 + c4] = make_uint2(pack2(v.x, v.y), pack2(v.z, v.w));
    atomicAdd(&cnorm[row], v.x * v.x + v.y * v.y + v.z * v.z + v.w * v.w);
  }
  __syncthreads();

  float lp = 0.f;
  const int nchunks = (count + 31) >> 5;
  for (int ch = 0; ch < nchunks; ++ch) {
    __syncthreads();
    if (t < 32) ridS[t] = (ch * 32 + t < count) ? bucket_rows[start + ch * 32 + t] : -1;
    __syncthreads();
#pragma unroll
    for (int i = 0; i < 2; ++i) {   // stage 32 z_f rows (bf16)
      int idx = t + i * 256;
      int row = idx >> 4, c8 = (idx & 15) << 3;
      int rid = ridS[row];
      uint4 v = make_uint4(0u, 0u, 0u, 0u);
      if (rid >= 0) v = *(const uint4*)&zf_bf[(size_t)rid * DD + c8];
      *(uint4*)&zfL[row * 136 + c8] = v;
    }
    __syncthreads();
    f32x4 acc[2][4];
#pragma unroll
    for (int m = 0; m < 2; ++m)
#pragma unroll
      for (int n = 0; n < 4; ++n) acc[m][n] = (f32x4){0.f, 0.f, 0.f, 0.f};
#pragma unroll
    for (int ks = 0; ks < 4; ++ks) {   // K=128
      const int lk = ks * 32 + (lhi << 3);
      bf16x8 a0 = *(const bf16x8*)&zfL[(l15) * 136 + lk];
      bf16x8 a1 = *(const bf16x8*)&zfL[(16 + l15) * 136 + lk];
#pragma unroll
      for (int n = 0; n < 4; ++n) {
        bf16x8 b = *(const bf16x8*)&Vb[(wid * 64 + n * 16 + l15) * 136 + lk];
        acc[0][n] = __builtin_amdgcn_mfma_f32_16x16x32_bf16(a0, b, acc[0][n], 0, 0, 0);
        acc[1][n] = __builtin_amdgcn_mfma_f32_16x16x32_bf16(a1, b, acc[1][n], 0, 0, 0);
      }
    }
#pragma unroll
    for (int m = 0; m < 2; ++m)
#pragma unroll
      for (int n = 0; n < 4; ++n)
#pragma unroll
        for (int r = 0; r < 4; ++r) {
          int row = m * 16 + (lhi << 2) + r;
          int col = wid * 64 + n * 16 + l15;
          dist[row * 257 + col] = cnorm[col] - 2.f * acc[m][n][r];
        }
    __syncthreads();
    {  // argmin over 256 codes: 8 threads per row
      const int r = t >> 3, seg = t & 7;
      float best = 3.4e38f; int bidx = 0;
#pragma unroll
      for (int j = 0; j < 32; ++j) {
        int c = seg * 32 + j;
        float d = dist[r * 257 + c];
        if (d < best) { best = d; bidx = c; }
      }
#pragma unroll
      for (int off = 1; off < 8; off <<= 1) {
        float od = __shfl_xor(best, off); int oi = __shfl_xor(bidx, off);
        if (od < best || (od == best && oi < bidx)) { best = od; bidx = oi; }
      }
      if (seg == 0) fiS[r] = bidx;
    }
    __syncthreads();
#pragma unroll
    for (int i = 0; i < 16; ++i) {   // zfq output + loss
      int e = t + i * 256;
      int row = e >> 7, col = e & 127;
      int rid = ridS[row];
      if (rid >= 0) {
        int fi = fiS[row];
        float q = fcb[((size_t)g * NK1 + fi) * DD + col];
        float z = bf2f(zfL[row * 136 + col]);
        out1[(size_t)rid * DD + col] = q;
        float d = q - z; lp += d * d;
      }
    }
  }
#pragma unroll
  for (int off = 1; off < 64; off <<= 1) lp += __shfl_xor(lp, off);
  if (lane == 0) redS[wid] = lp;
  __syncthreads();
  if (t == 0) fine_partial[g] = redS[0] + redS[1] + redS[2] + redS[3];
}

// ---------------- Kernel 4: deterministic loss reduce ----------------------
__global__ void k_final(const float* __restrict__ coarse_partial,
                        const float* __restrict__ fine_partial,
                        float* __restrict__ outL) {
  if (threadIdx.x == 0) {
    float s = 0.f;
    for (int i = 0; i < 128; ++i) s += coarse_partial[i];
    for (int g = 0; g < NK0; ++g) s += fine_partial[g];
    outL[0] = 1.25f * s / 1048576.0f;   // 1.25*(mean_c + mean_f), B*128
  }
}

// ---------------- launcher -------------------------------------------------
extern "C" void kernel_launch(void* const* d_in, const int* in_sizes, int n_in,
                              void* d_out, int out_size, void* d_ws, size_t ws_size,
                              hipStream_t stream) {
  const float* x     = (const float*)d_in[0];
  const float* Wc    = (const float*)d_in[1];
  const float* bc    = (const float*)d_in[2];
  const float* gc    = (const float*)d_in[3];
  const float* betac = (const float*)d_in[4];
  const float* ccb   = (const float*)d_in[5];
  const float* Wf    = (const float*)d_in[6];
  const float* bfv   = (const float*)d_in[7];
  const float* gf    = (const float*)d_in[8];
  const float* betaf = (const float*)d_in[9];
  const float* fcb   = (const float*)d_in[10];

  float* out0 = (float*)d_out;                 // zcq_st [8192,128]
  float* out1 = out0 + (size_t)NB * DD;        // zfq_st [8192,128]
  float* outL = out0 + (size_t)2 * NB * DD;    // loss scalar

  char* ws = (char*)d_ws;
  unsigned short* zcq_bf = (unsigned short*)(ws);
  unsigned short* zf_bf  = (unsigned short*)(ws + 2097152);
  int* ci_g        = (int*)(ws + 4194304);
  int* bucket_rows = (int*)(ws + 4227072);
  int* counts      = (int*)(ws + 4259840);
  int* offsets     = (int*)(ws + 4260096);
  int* cursor      = (int*)(ws + 4260352);
  float* coarse_partial = (float*)(ws + 4260608);
  float* fine_partial   = (float*)(ws + 4261120);

  hipFuncSetAttribute(reinterpret_cast<const void*>(k1_gemm_ln_coarse),
                      hipFuncAttributeMaxDynamicSharedMemorySize, 70688);
  hipFuncSetAttribute(reinterpret_cast<const void*>(k3_fine),
                      hipFuncAttributeMaxDynamicSharedMemorySize, 112640);

  hipMemsetAsync(ws + 4259840, 0, 1536, stream);

  hipLaunchKernelGGL(k1_gemm_ln_coarse, dim3(NB / 64), dim3(256), 70688, stream,
                     x, Wc, bc, gc, betac, ccb, out0, zcq_bf, ci_g, counts, coarse_partial);
  hipLaunchKernelGGL(k2_gemm_ln, dim3(NB / 64), dim3(256), 33792, stream,
                     x, zcq_bf, Wf, bfv, gf, betaf, zf_bf);
  hipLaunchKernelGGL(k_prefix, dim3(1), dim3(64), 0, stream, counts, offsets, cursor);
  hipLaunchKernelGGL(k_scatter, dim3(NB / 256), dim3(256), 0, stream, ci_g, cursor, bucket_rows);
  hipLaunchKernelGGL(k3_fine, dim3(NK0), dim3(256), 112640, stream,
                     zf_bf, fcb, counts, offsets, bucket_rows, out1, fine_partial);
  hipLaunchKernelGGL(k_final, dim3(1), dim3(64), 0, stream, coarse_partial, fine_partial, outL);
}

// Round 2
// 146.927 us; speedup vs baseline: 1.4321x; 1.4321x over previous
//
#include <hip/hip_runtime.h>

#define NB   8192
#define HD   1024
#define HFD  1152
#define NK0  64
#define NK1  256
#define DD   128

typedef __attribute__((ext_vector_type(4))) float  f32x4;
typedef __attribute__((ext_vector_type(8))) __bf16 bf16x8;

__device__ __forceinline__ unsigned short f2bf(float f) {
  unsigned int u = __float_as_uint(f);
  u += 0x7fffu + ((u >> 16) & 1u);
  return (unsigned short)(u >> 16);
}
__device__ __forceinline__ float bf2f(unsigned short h) {
  return __uint_as_float(((unsigned int)h) << 16);
}
__device__ __forceinline__ unsigned int pack2(float a, float b) {
  return (unsigned int)f2bf(a) | ((unsigned int)f2bf(b) << 16);
}
__device__ __forceinline__ uint4 pack8(const float4 a, const float4 b) {
  return make_uint4(pack2(a.x, a.y), pack2(a.z, a.w), pack2(b.x, b.y), pack2(b.z, b.w));
}

// ---- K0: f32 -> bf16 conversions + fine-codebook norms --------------------
// blocks [0,4096): x   [4096,4160): Wc   [4160,4232): Wf   [4232,5256): fcb
// blocks [5256,5320): fine-code norms (thread = code row)
__global__ __launch_bounds__(256) void k0_convert(
    const float* __restrict__ x, const float* __restrict__ Wc,
    const float* __restrict__ Wf, const float* __restrict__ fcb,
    unsigned short* __restrict__ xbf, unsigned short* __restrict__ Wcbf,
    unsigned short* __restrict__ Wfbf, unsigned short* __restrict__ fcbbf,
    float* __restrict__ cn_all)
{
  const int bid = blockIdx.x, t = threadIdx.x;
  const float* src; unsigned short* dst; long e0;
  if (bid < 4096)      { src = x;   dst = xbf;   e0 = ((long)bid * 256 + t) * 8; }
  else if (bid < 4160) { src = Wc;  dst = Wcbf;  e0 = ((long)(bid - 4096) * 256 + t) * 8; }
  else if (bid < 4232) { src = Wf;  dst = Wfbf;  e0 = ((long)(bid - 4160) * 256 + t) * 8; }
  else if (bid < 5256) { src = fcb; dst = fcbbf; e0 = ((long)(bid - 4232) * 256 + t) * 8; }
  else {
    const int row = (bid - 5256) * 256 + t;
    const float* r = fcb + (size_t)row * DD;
    float s = 0.f;
#pragma unroll
    for (int i = 0; i < 32; ++i) {
      const float4 v = *(const float4*)&r[i * 4];
      s += v.x * v.x + v.y * v.y + v.z * v.z + v.w * v.w;
    }
    cn_all[row] = s;
    return;
  }
  const float4 a = *(const float4*)&src[e0];
  const float4 b = *(const float4*)&src[e0 + 4];
  *(uint4*)&dst[e0] = pack8(a, b);
}

// ---- K12: blocks 0..127 = GEMM1+LN+coarseVQ; 128..255 = GEMM2a partial ----
// BM=64, BN=128, BK=64, 4 waves, reg-staged 1-deep lookahead (T14).
__global__ __launch_bounds__(256) void k12_gemm(
    const unsigned short* __restrict__ xbf, const unsigned short* __restrict__ Wcbf,
    const unsigned short* __restrict__ Wfbf,
    const float* __restrict__ bc, const float* __restrict__ gc,
    const float* __restrict__ betac, const float* __restrict__ ccb,
    float* __restrict__ out0, unsigned short* __restrict__ zcq_bf,
    int* __restrict__ ci_g, int* __restrict__ counts,
    float* __restrict__ coarse_partial, float* __restrict__ p2a)
{
  extern __shared__ char smem[];
  unsigned short* As = (unsigned short*)smem;             // [64][72] bf16
  unsigned short* Bs = (unsigned short*)(smem + 9216);    // [128][72] bf16
  // role-0 post-phase overlay:
  float* zcf           = (float*)smem;                    // [64][132] f32 (33792)
  unsigned short* cbb  = (unsigned short*)(smem + 33792); // [64][136] bf16
  unsigned short* zbb  = (unsigned short*)(smem + 51200); // [64][136] bf16
  float* cnorm = (float*)(smem + 68608);                  // [64]
  float* dmS   = (float*)(smem + 68864);                  // [4][64]
  int*   imS   = (int*)  (smem + 69888);                  // [4][64]
  int*   cxS   = (int*)  (smem + 70912);                  // [64]
  float* redS  = (float*)(smem + 71168);                  // [4]

  const int t = threadIdx.x, lane = t & 63, wid = t >> 6;
  const int wm = wid & 1, wn = wid >> 1, l15 = lane & 15, lhi = lane >> 4;
  const int role = (blockIdx.x >= 128) ? 1 : 0;
  const int m0 = (blockIdx.x & 127) * 64;
  const unsigned short* Wb = role ? Wfbf : Wcbf;
  const int ldb = role ? HFD : HD;
  const int sr = t >> 3, sc = (t & 7) * 8;   // staging map

  f32x4 acc[2][4];
#pragma unroll
  for (int m = 0; m < 2; ++m)
#pragma unroll
    for (int n = 0; n < 4; ++n) acc[m][n] = (f32x4){0.f, 0.f, 0.f, 0.f};

  uint4 ra[2], rb[4];
#define LOADT(kt)                                                              \
  {                                                                            \
    const unsigned short* ap = &xbf[(size_t)(m0 + sr) * HD + (kt) * 64 + sc];  \
    ra[0] = *(const uint4*)ap;                                                 \
    ra[1] = *(const uint4*)(ap + 32 * HD);                                     \
    const unsigned short* bp = &Wb[(size_t)sr * ldb + (kt) * 64 + sc];         \
    rb[0] = *(const uint4*)bp;              rb[1] = *(const uint4*)(bp + 32 * ldb); \
    rb[2] = *(const uint4*)(bp + 64 * ldb); rb[3] = *(const uint4*)(bp + 96 * ldb); \
  }

  LOADT(0);
  for (int kt = 0; kt < 16; ++kt) {
    __syncthreads();
    *(uint4*)&As[sr * 72 + sc]        = ra[0];
    *(uint4*)&As[(sr + 32) * 72 + sc] = ra[1];
#pragma unroll
    for (int i = 0; i < 4; ++i) *(uint4*)&Bs[(sr + i * 32) * 72 + sc] = rb[i];
    if (kt < 15) LOADT(kt + 1);
    __syncthreads();
#pragma unroll
    for (int ks = 0; ks < 2; ++ks) {
      const int lk = ks * 32 + (lhi << 3);
      bf16x8 a0 = *(const bf16x8*)&As[(wm * 32 + l15) * 72 + lk];
      bf16x8 a1 = *(const bf16x8*)&As[(wm * 32 + 16 + l15) * 72 + lk];
#pragma unroll
      for (int n = 0; n < 4; ++n) {
        bf16x8 b = *(const bf16x8*)&Bs[(wn * 64 + n * 16 + l15) * 72 + lk];
        acc[0][n] = __builtin_amdgcn_mfma_f32_16x16x32_bf16(a0, b, acc[0][n], 0, 0, 0);
        acc[1][n] = __builtin_amdgcn_mfma_f32_16x16x32_bf16(a1, b, acc[1][n], 0, 0, 0);
      }
    }
  }
#undef LOADT

  if (role) {  // GEMM2a: write fp32 partial
#pragma unroll
    for (int m = 0; m < 2; ++m)
#pragma unroll
      for (int n = 0; n < 4; ++n)
#pragma unroll
        for (int r = 0; r < 4; ++r) {
          int row = wm * 32 + m * 16 + lhi * 4 + r;
          int col = wn * 64 + n * 16 + l15;
          p2a[(size_t)(m0 + row) * DD + col] = acc[m][n][r];
        }
    return;
  }

  // ---- role 0 epilogue ----
  if (t < 64) cnorm[t] = 0.f;      // region disjoint from staging LDS
  __syncthreads();                 // all MFMA LDS reads done; staging dead
#pragma unroll
  for (int m = 0; m < 2; ++m)
#pragma unroll
    for (int n = 0; n < 4; ++n)
#pragma unroll
      for (int r = 0; r < 4; ++r) {
        int row = wm * 32 + m * 16 + lhi * 4 + r;
        int col = wn * 64 + n * 16 + l15;
        zcf[row * 132 + col] = acc[m][n][r] + bc[col];
      }
#pragma unroll
  for (int i = 0; i < 8; ++i) {    // stage coarse cb bf16 + fp32 norms
    int idx = t + i * 256;
    int row = idx >> 5, c4 = (idx & 31) << 2;
    const float4 v = *(const float4*)&ccb[row * DD + c4];
    *(uint2*)&cbb[row * 136 + c4] = make_uint2(pack2(v.x, v.y), pack2(v.z, v.w));
    atomicAdd(&cnorm[row], v.x * v.x + v.y * v.y + v.z * v.z + v.w * v.w);
  }
  __syncthreads();
  {  // LayerNorm (4 thr/row) + z -> bf16 LDS
    const int r = t >> 2, p = t & 3;
    float* zr = &zcf[r * 132 + p * 32];
    float z2[32];
    float s = 0.f, s2 = 0.f;
#pragma unroll
    for (int j = 0; j < 32; ++j) { float v = zr[j]; z2[j] = v; s += v; s2 += v * v; }
    s  += __shfl_xor(s, 1);  s  += __shfl_xor(s, 2);
    s2 += __shfl_xor(s2, 1); s2 += __shfl_xor(s2, 2);
    const float mu   = s * (1.f / 128.f);
    const float rstd = rsqrtf(s2 * (1.f / 128.f) - mu * mu + 1e-5f);
#pragma unroll
    for (int j = 0; j < 32; ++j) {
      int col = p * 32 + j;
      float v = (z2[j] - mu) * rstd * gc[col] + betac[col];
      z2[j] = v; zr[j] = v;
    }
#pragma unroll
    for (int jj = 0; jj < 16; ++jj)
      *(unsigned int*)&zbb[r * 136 + p * 32 + 2 * jj] = pack2(z2[2 * jj], z2[2 * jj + 1]);
  }
  __syncthreads();
  {  // coarse distances via MFMA: D[code][zrow], wave wid owns codes wid*16..+15
    f32x4 dacc[4];
#pragma unroll
    for (int n = 0; n < 4; ++n) dacc[n] = (f32x4){0.f, 0.f, 0.f, 0.f};
#pragma unroll
    for (int ks = 0; ks < 4; ++ks) {
      const int lk = ks * 32 + (lhi << 3);
      bf16x8 a = *(const bf16x8*)&cbb[(wid * 16 + l15) * 136 + lk];
#pragma unroll
      for (int n = 0; n < 4; ++n) {
        bf16x8 b = *(const bf16x8*)&zbb[(n * 16 + l15) * 136 + lk];
        dacc[n] = __builtin_amdgcn_mfma_f32_16x16x32_bf16(a, b, dacc[n], 0, 0, 0);
      }
    }
#pragma unroll
    for (int n = 0; n < 4; ++n) {
      float bd = 3.4e38f; int bi = 0;
#pragma unroll
      for (int r = 0; r < 4; ++r) {
        int code = wid * 16 + lhi * 4 + r;
        float d = cnorm[code] - 2.f * dacc[n][r];
        if (d < bd || (d == bd && code < bi)) { bd = d; bi = code; }
      }
#pragma unroll
      for (int off = 16; off < 64; off <<= 1) {
        float od = __shfl_xor(bd, off); int oi = __shfl_xor(bi, off);
        if (od < bd || (od == bd && oi < bi)) { bd = od; bi = oi; }
      }
      if (lhi == 0) { dmS[wid * 64 + n * 16 + l15] = bd; imS[wid * 64 + n * 16 + l15] = bi; }
    }
  }
  __syncthreads();
  if (t < 64) {
    float best = dmS[t]; int bidx = imS[t];
#pragma unroll
    for (int w = 1; w < 4; ++w) {
      float d = dmS[w * 64 + t]; int i2 = imS[w * 64 + t];
      if (d < best || (d == best && i2 < bidx)) { best = d; bidx = i2; }
    }
    ci_g[m0 + t] = bidx;
    atomicAdd(&counts[bidx], 1);
    cxS[t] = bidx;
  }
  __syncthreads();
  float lp = 0.f;
#pragma unroll
  for (int i = 0; i < 32; ++i) {
    int e = t + i * 256;
    int r = e >> 7, col = e & 127;
    int c = cxS[r];
    float q = ccb[c * DD + col];
    float z = zcf[r * 132 + col];
    out0[(size_t)(m0 + r) * DD + col]   = q;
    zcq_bf[(size_t)(m0 + r) * DD + col] = f2bf(q);
    float d = q - z; lp += d * d;
  }
#pragma unroll
  for (int off = 1; off < 64; off <<= 1) lp += __shfl_xor(lp, off);
  if (lane == 0) redS[wid] = lp;
  __syncthreads();
  if (t == 0) coarse_partial[blockIdx.x] = redS[0] + redS[1] + redS[2] + redS[3];
}

// ---- K2b: zf = LN(partial + zcq @ Wfz^T + bias) ---------------------------
__global__ __launch_bounds__(256) void k2b(
    const unsigned short* __restrict__ zcq_bf, const unsigned short* __restrict__ Wfbf,
    const float* __restrict__ p2a, const float* __restrict__ bfv,
    const float* __restrict__ gf, const float* __restrict__ betaf,
    unsigned short* __restrict__ zf_bf)
{
  extern __shared__ char smem[];
  unsigned short* Zq = (unsigned short*)smem;             // [64][136]
  unsigned short* Wz = (unsigned short*)(smem + 17408);   // [128][136]
  float* zff = (float*)smem;                              // [64][132] overlay

  const int t = threadIdx.x, lane = t & 63, wid = t >> 6;
  const int wm = wid & 1, wn = wid >> 1, l15 = lane & 15, lhi = lane >> 4;
  const int m0 = blockIdx.x * 64;

#pragma unroll
  for (int i = 0; i < 4; ++i) {
    int idx = t + i * 256; int row = idx >> 4, c8 = (idx & 15) * 8;
    *(uint4*)&Zq[row * 136 + c8] = *(const uint4*)&zcq_bf[(size_t)(m0 + row) * DD + c8];
  }
#pragma unroll
  for (int i = 0; i < 8; ++i) {
    int idx = t + i * 256; int row = idx >> 4, c8 = (idx & 15) * 8;
    *(uint4*)&Wz[row * 136 + c8] = *(const uint4*)&Wfbf[(size_t)row * HFD + 1024 + c8];
  }
  __syncthreads();
  f32x4 acc[2][4];
#pragma unroll
  for (int m = 0; m < 2; ++m)
#pragma unroll
    for (int n = 0; n < 4; ++n) acc[m][n] = (f32x4){0.f, 0.f, 0.f, 0.f};
#pragma unroll
  for (int ks = 0; ks < 4; ++ks) {
    const int lk = ks * 32 + (lhi << 3);
    bf16x8 a0 = *(const bf16x8*)&Zq[(wm * 32 + l15) * 136 + lk];
    bf16x8 a1 = *(const bf16x8*)&Zq[(wm * 32 + 16 + l15) * 136 + lk];
#pragma unroll
    for (int n = 0; n < 4; ++n) {
      bf16x8 b = *(const bf16x8*)&Wz[(wn * 64 + n * 16 + l15) * 136 + lk];
      acc[0][n] = __builtin_amdgcn_mfma_f32_16x16x32_bf16(a0, b, acc[0][n], 0, 0, 0);
      acc[1][n] = __builtin_amdgcn_mfma_f32_16x16x32_bf16(a1, b, acc[1][n], 0, 0, 0);
    }
  }
  __syncthreads();
#pragma unroll
  for (int m = 0; m < 2; ++m)
#pragma unroll
    for (int n = 0; n < 4; ++n)
#pragma unroll
      for (int r = 0; r < 4; ++r) {
        int row = wm * 32 + m * 16 + lhi * 4 + r;
        int col = wn * 64 + n * 16 + l15;
        zff[row * 132 + col] = acc[m][n][r] + p2a[(size_t)(m0 + row) * DD + col] + bfv[col];
      }
  __syncthreads();
  {  // LN + bf16 out
    const int r = t >> 2, p = t & 3;
    const float* zr = &zff[r * 132 + p * 32];
    float z2[32];
    float s = 0.f, s2 = 0.f;
#pragma unroll
    for (int j = 0; j < 32; ++j) { float v = zr[j]; z2[j] = v; s += v; s2 += v * v; }
    s  += __shfl_xor(s, 1);  s  += __shfl_xor(s, 2);
    s2 += __shfl_xor(s2, 1); s2 += __shfl_xor(s2, 2);
    const float mu   = s * (1.f / 128.f);
    const float rstd = rsqrtf(s2 * (1.f / 128.f) - mu * mu + 1e-5f);
    unsigned int o[16];
#pragma unroll
    for (int jj = 0; jj < 16; ++jj) {
      int col = p * 32 + 2 * jj;
      float v0 = (z2[2 * jj]     - mu) * rstd * gf[col]     + betaf[col];
      float v1 = (z2[2 * jj + 1] - mu) * rstd * gf[col + 1] + betaf[col + 1];
      o[jj] = pack2(v0, v1);
    }
#pragma unroll
    for (int q = 0; q < 4; ++q)
      *(uint4*)&zf_bf[(size_t)(m0 + r) * DD + p * 32 + q * 8] =
          make_uint4(o[q * 4], o[q * 4 + 1], o[q * 4 + 2], o[q * 4 + 3]);
  }
}

// ---- bucketing ------------------------------------------------------------
__global__ void k_prefix(const int* __restrict__ counts, int* __restrict__ offsets,
                         int* __restrict__ cursor) {
  if (threadIdx.x == 0) {
    int run = 0;
    for (int g = 0; g < NK0; ++g) { offsets[g] = run; cursor[g] = run; run += counts[g]; }
  }
}
__global__ void k_scatter(const int* __restrict__ ci_g, int* __restrict__ cursor,
                          int* __restrict__ bucket_rows) {
  int i = blockIdx.x * 256 + threadIdx.x;
  int pos = atomicAdd(&cursor[ci_g[i]], 1);
  bucket_rows[pos] = i;
}

// ---- K3: per-(group,chunk) fine VQ ----------------------------------------
__global__ __launch_bounds__(256) void k3_fine(
    const unsigned short* __restrict__ zf_bf, const unsigned short* __restrict__ fcbbf,
    const float* __restrict__ fcb, const float* __restrict__ cn_all,
    const int* __restrict__ counts, const int* __restrict__ offsets,
    const int* __restrict__ bucket_rows,
    float* __restrict__ out1, float* __restrict__ fine_partial)
{
  extern __shared__ char smem[];
  unsigned short* Vb  = (unsigned short*)smem;            // [256][136]
  unsigned short* zfL = (unsigned short*)(smem + 69632);  // [32][136]
  int*   ridS = (int*)  (smem + 78336);                   // [32]
  float* dmS  = (float*)(smem + 78464);                   // [4][32]
  int*   imS  = (int*)  (smem + 78976);                   // [4][32]
  int*   fiS  = (int*)  (smem + 79488);                   // [32]
  float* redS = (float*)(smem + 79616);                   // [4]

  const int g = blockIdx.y, cx = blockIdx.x;
  const int t = threadIdx.x, lane = t & 63, wid = t >> 6;
  const int l15 = lane & 15, lhi = lane >> 4;
  const int count = counts[g], start = offsets[g];
  if (cx * 32 >= count) return;

#pragma unroll
  for (int i = 0; i < 8; ++i) {   // stage group codebook bf16
    int idx = t + i * 256; int row = idx >> 3, c8 = (idx & 7) * 8;
    *(uint4*)&Vb[row * 136 + c8] = *(const uint4*)&fcbbf[((size_t)g * NK1 + row) * DD + c8];
  }
  float cnr[4];
#pragma unroll
  for (int n = 0; n < 4; ++n) cnr[n] = cn_all[g * NK1 + wid * 64 + n * 16 + l15];

  float lp = 0.f;
  for (int r0 = cx * 32; r0 < count; r0 += 256) {
    __syncthreads();
    if (t < 32) ridS[t] = (r0 + t < count) ? bucket_rows[start + r0 + t] : -1;
    __syncthreads();
#pragma unroll
    for (int i = 0; i < 2; ++i) {
      int idx = t + i * 256; int row = idx >> 4, c8 = (idx & 15) * 8;
      int rid = ridS[row];
      uint4 v = make_uint4(0u, 0u, 0u, 0u);
      if (rid >= 0) v = *(const uint4*)&zf_bf[(size_t)rid * DD + c8];
      *(uint4*)&zfL[row * 136 + c8] = v;
    }
    __syncthreads();
    f32x4 acc[2][4];
#pragma unroll
    for (int m = 0; m < 2; ++m)
#pragma unroll
      for (int n = 0; n < 4; ++n) acc[m][n] = (f32x4){0.f, 0.f, 0.f, 0.f};
#pragma unroll
    for (int ks = 0; ks < 4; ++ks) {
      const int lk = ks * 32 + (lhi << 3);
      bf16x8 a0 = *(const bf16x8*)&zfL[(l15) * 136 + lk];
      bf16x8 a1 = *(const bf16x8*)&zfL[(16 + l15) * 136 + lk];
#pragma unroll
      for (int n = 0; n < 4; ++n) {
        bf16x8 b = *(const bf16x8*)&Vb[(wid * 64 + n * 16 + l15) * 136 + lk];
        acc[0][n] = __builtin_amdgcn_mfma_f32_16x16x32_bf16(a0, b, acc[0][n], 0, 0, 0);
        acc[1][n] = __builtin_amdgcn_mfma_f32_16x16x32_bf16(a1, b, acc[1][n], 0, 0, 0);
      }
    }
#pragma unroll
    for (int m = 0; m < 2; ++m)
#pragma unroll
      for (int r = 0; r < 4; ++r) {
        float bd = 3.4e38f; int bi = 0;
#pragma unroll
        for (int n = 0; n < 4; ++n) {
          int code = wid * 64 + n * 16 + l15;
          float d = cnr[n] - 2.f * acc[m][n][r];
          if (d < bd || (d == bd && code < bi)) { bd = d; bi = code; }
        }
#pragma unroll
        for (int off = 1; off < 16; off <<= 1) {
          float od = __shfl_xor(bd, off); int oi = __shfl_xor(bi, off);
          if (od < bd || (od == bd && oi < bi)) { bd = od; bi = oi; }
        }
        if (l15 == 0) {
          int row = m * 16 + lhi * 4 + r;
          dmS[wid * 32 + row] = bd; imS[wid * 32 + row] = bi;
        }
      }
    __syncthreads();
    if (t < 32) {
      float bd = dmS[t]; int bi = imS[t];
#pragma unroll
      for (int w = 1; w < 4; ++w) {
        float od = dmS[w * 32 + t]; int oi = imS[w * 32 + t];
        if (od < bd || (od == bd && oi < bi)) { bd = od; bi = oi; }
      }
      fiS[t] = bi;
    }
    __syncthreads();
#pragma unroll
    for (int i = 0; i < 16; ++i) {
      int e = t + i * 256; int row = e >> 7, col = e & 127;
      int rid = ridS[row];
      if (rid >= 0) {
        int fi = fiS[row];
        float q = fcb[((size_t)g * NK1 + fi) * DD + col];
        float z = bf2f(zfL[row * 136 + col]);
        out1[(size_t)rid * DD + col] = q;
        float d = q - z; lp += d * d;
      }
    }
  }
#pragma unroll
  for (int off = 1; off < 64; off <<= 1) lp += __shfl_xor(lp, off);
  if (lane == 0) redS[wid] = lp;
  __syncthreads();
  if (t == 0) fine_partial[g * 8 + cx] = redS[0] + redS[1] + redS[2] + redS[3];
}

// ---- K4: deterministic loss reduce ----------------------------------------
__global__ void k_final(const float* __restrict__ coarse_partial,
                        const float* __restrict__ fine_partial,
                        float* __restrict__ outL) {
  if (threadIdx.x == 0) {
    float s = 0.f;
    for (int i = 0; i < 128; ++i) s += coarse_partial[i];
    for (int i = 0; i < 512; ++i) s += fine_partial[i];
    outL[0] = 1.25f * s / 1048576.0f;
  }
}

// ---- launcher -------------------------------------------------------------
extern "C" void kernel_launch(void* const* d_in, const int* in_sizes, int n_in,
                              void* d_out, int out_size, void* d_ws, size_t ws_size,
                              hipStream_t stream) {
  const float* x     = (const float*)d_in[0];
  const float* Wc    = (const float*)d_in[1];
  const float* bc    = (const float*)d_in[2];
  const float* gc    = (const float*)d_in[3];
  const float* betac = (const float*)d_in[4];
  const float* ccb   = (const float*)d_in[5];
  const float* Wf    = (const float*)d_in[6];
  const float* bfv   = (const float*)d_in[7];
  const float* gf    = (const float*)d_in[8];
  const float* betaf = (const float*)d_in[9];
  const float* fcb   = (const float*)d_in[10];

  float* out0 = (float*)d_out;
  float* out1 = out0 + (size_t)NB * DD;
  float* outL = out0 + (size_t)2 * NB * DD;

  char* ws = (char*)d_ws;
  unsigned short* xbf    = (unsigned short*)(ws);
  unsigned short* Wcbf   = (unsigned short*)(ws + 16777216);
  unsigned short* Wfbf   = (unsigned short*)(ws + 17039360);
  unsigned short* fcbbf  = (unsigned short*)(ws + 17334272);
  float*          cn_all = (float*)(ws + 21528576);
  float*          p2a    = (float*)(ws + 21594112);
  unsigned short* zcq_bf = (unsigned short*)(ws + 25788416);
  unsigned short* zf_bf  = (unsigned short*)(ws + 27885568);
  int* ci_g        = (int*)(ws + 29982720);
  int* bucket_rows = (int*)(ws + 30015488);
  int* counts      = (int*)(ws + 30048256);
  int* offsets     = (int*)(ws + 30048512);
  int* cursor      = (int*)(ws + 30048768);
  float* coarse_partial = (float*)(ws + 30049024);
  float* fine_partial   = (float*)(ws + 30049536);

  hipFuncSetAttribute(reinterpret_cast<const void*>(k12_gemm),
                      hipFuncAttributeMaxDynamicSharedMemorySize, 71200);
  hipFuncSetAttribute(reinterpret_cast<const void*>(k3_fine),
                      hipFuncAttributeMaxDynamicSharedMemorySize, 79648);
  hipFuncSetAttribute(reinterpret_cast<const void*>(k2b),
                      hipFuncAttributeMaxDynamicSharedMemorySize, 52240);

  hipMemsetAsync(ws + 30048256, 0, 3328, stream);

  hipLaunchKernelGGL(k0_convert, dim3(5320), dim3(256), 0, stream,
                     x, Wc, Wf, fcb, xbf, Wcbf, Wfbf, fcbbf, cn_all);
  hipLaunchKernelGGL(k12_gemm, dim3(256), dim3(256), 71200, stream,
                     xbf, Wcbf, Wfbf, bc, gc, betac, ccb,
                     out0, zcq_bf, ci_g, counts, coarse_partial, p2a);
  hipLaunchKernelGGL(k2b, dim3(128), dim3(256), 52240, stream,
                     zcq_bf, Wfbf, p2a, bfv, gf, betaf, zf_bf);
  hipLaunchKernelGGL(k_prefix, dim3(1), dim3(64), 0, stream, counts, offsets, cursor);
  hipLaunchKernelGGL(k_scatter, dim3(NB / 256), dim3(256), 0, stream, ci_g, cursor, bucket_rows);
  hipLaunchKernelGGL(k3_fine, dim3(8, 64), dim3(256), 79648, stream,
                     zf_bf, fcbbf, fcb, cn_all, counts, offsets, bucket_rows, out1, fine_partial);
  hipLaunchKernelGGL(k_final, dim3(1), dim3(64), 0, stream, coarse_partial, fine_partial, outL);
}